// Round 7
// baseline (5713.088 us; speedup 1.0000x reference)
//
#include <hip/hip_runtime.h>
#include <hip/hip_bf16.h>

// DelayRNN on MI355X — Round 21: R20 (intra-XCD exchange via L2 atomics) with
// the asm encoding fixed: global_* offset imm is 13-bit SIGNED (max 4095), so
// the second 4KB half of the slab is addressed via a second VGPR (o1), not
// offset:4096/4104. R19 measured 1347us (one LLC hop/step); atomics execute
// AT the shared XCD L2 (group same-XCD verified in-band at t=1 since R19):
//   * publish: non-returning global_atomic_swap_x2 into the slab (L2-local)
//     + sc0 sc1 mirror store (keeps the LLC fallback tier viable).
//   * poll:    returning global_atomic_or_x2(0) sc0 — L2-fresh fused
//     detect+fetch, no staleness window (unlike plain sc0 loads, R18).
//   * fallback: capped LLC poll reads the MIRROR when coh; sticky-dead
//     wedge-proofing throughout (R18/R19 discipline).
// Weights in 120 VGPRs, 8 groups x 4 batches, 8KB slab, 319 steps, tail
// decode GEMM — all R19 verbatim.

constexpr int kB    = 32;
constexpr int kS    = 256;
constexpr int kI    = 128;
constexpr int kH    = 512;
constexpr int kC    = 64;
constexpr int kOutL = 64;
constexpr int kMaxD = 16;
constexpr int kBufD = 17;
constexpr int kNWG  = 256;
constexpr int kJPW  = 16;
constexpr int kGrp  = 8;                 // groups (ideally == XCDs)
constexpr int kBpG  = kB / kGrp;         // 4 batches per group
constexpr int kWrd  = kBpG * kH;         // 2048 tagged u32 per group slab (8KB)
constexpr int kSteps = kS + kOutL - 1;   // 319: last needed publish is t=318
constexpr int kKz   = kH + kI;           // 640
constexpr int kZPad = 8;                 // zs row stride 648 elem (1296 B)
constexpr int      kFastSpin = 512;      // atomic poll rounds (~0.15us each)
constexpr unsigned kSpinCap  = 131072;   // LLC poll cap — wedge-proof
constexpr unsigned kTagMask  = 0x01ff0000u;  // tag bits 24:16 (tags <= 319)
constexpr unsigned kXccMask  = 0x0e000000u;  // XCC_ID bits 27:25

typedef __bf16 bf16x8 __attribute__((ext_vector_type(8)));
typedef float  f32x4  __attribute__((ext_vector_type(4)));
typedef unsigned int u32x4 __attribute__((ext_vector_type(4)));

__device__ __forceinline__ f32x4 MFMA(bf16x8 a, bf16x8 b, f32x4 c) {
  return __builtin_amdgcn_mfma_f32_16x16x32_bf16(a, b, c, 0, 0, 0);
}
__device__ __forceinline__ bf16x8 ld8(const __hip_bfloat16* p) {
  return *reinterpret_cast<const bf16x8*>(p);
}
__device__ __forceinline__ bf16x8 ld8_f32(const float* p) {
  float4 a = *(const float4*)p, b = *(const float4*)(p + 4);
  union { __hip_bfloat16 h[8]; bf16x8 v; } c;
  c.h[0] = __float2bfloat16(a.x); c.h[1] = __float2bfloat16(a.y);
  c.h[2] = __float2bfloat16(a.z); c.h[3] = __float2bfloat16(a.w);
  c.h[4] = __float2bfloat16(b.x); c.h[5] = __float2bfloat16(b.y);
  c.h[6] = __float2bfloat16(b.z); c.h[7] = __float2bfloat16(b.w);
  return c.v;
}
__device__ __forceinline__ float sigm(float x) { return 1.0f / (1.0f + __expf(-x)); }

// ---------------- prep kernels (validated R2-R12, unchanged) ----------------

__global__ void prep_cast(const float* x, const float* W_in, const float* W_pass,
                          const float* W_tau, const float* W_mem, const float* W_out,
                          __hip_bfloat16* xb, __hip_bfloat16* Wall, __hip_bfloat16* BtP,
                          __hip_bfloat16* BtT, __hip_bfloat16* BtM, __hip_bfloat16* WtOut) {
  const int tid = blockIdx.x * blockDim.x + threadIdx.x;
  const int nth = gridDim.x * blockDim.x;
  for (int i = tid; i < kB * kS * kI; i += nth) xb[i] = __float2bfloat16(x[i]);
  for (int i = tid; i < kH * kKz; i += nth) {
    int j = i / kKz, k = i - j * kKz;
    Wall[i] = __float2bfloat16(W_in[k * kH + j]);
  }
  for (int i = tid; i < kH * kH; i += nth) {
    int j = i >> 9, k = i & 511;
    BtP[i] = __float2bfloat16(W_pass[k * kH + j]);
    BtT[i] = __float2bfloat16(W_tau[k * kH + j]);
    BtM[i] = __float2bfloat16(W_mem[k * kH + j]);
  }
  for (int i = tid; i < kC * kH; i += nth) {
    int c = i >> 9, k = i & 511;
    WtOut[i] = __float2bfloat16(W_out[k * kC + c]);
  }
}

__global__ void prep_bias(const float* b_in, const float* b_pass, const float* b_tau,
                          const float* b_mem, const float* W_pass, const float* W_tau,
                          const float* W_mem, float* bias) {
  __shared__ float bp_s[kH];
  const int j = threadIdx.x;
  float s1 = 0.f, s2 = 0.f, s3 = 0.f;
  for (int k = 0; k < kH; ++k) {
    float bi = b_in[k];
    s1 += bi * W_pass[k * kH + j];
    s2 += bi * W_tau[k * kH + j];
    s3 += bi * W_mem[k * kH + j];
  }
  float bP = s1 + b_pass[j];
  bias[j]          = b_in[j];
  bias[kH + j]     = bP;
  bias[2 * kH + j] = s2 + b_tau[j];
  bias[4 * kH + j] = s3 + b_mem[j];
  bp_s[j] = bP;
  __syncthreads();
  float s4 = 0.f, s5 = 0.f;
  for (int k = 0; k < kH; ++k) {
    float v = bp_s[k];
    s4 += v * W_tau[k * kH + j];
    s5 += v * W_mem[k * kH + j];
  }
  bias[3 * kH + j] = s4 + b_tau[j];
  bias[5 * kH + j] = s5 + b_mem[j];
}

__global__ __launch_bounds__(64) void prep_mm1(const float* W_in, const __hip_bfloat16* BtP,
    const __hip_bfloat16* BtT, const __hip_bfloat16* BtM,
    __hip_bfloat16* Wall, __hip_bfloat16* Cip) {
  const int bm = blockIdx.x, bn = blockIdx.y, z = blockIdx.z;
  const int lane = threadIdx.x;
  const int kq = (lane >> 4) * 8;
  const __hip_bfloat16* Bt = (z == 0) ? BtP : (z == 1 ? BtT : BtM);
  const int mat = (z == 0) ? 1 : (z == 1 ? 2 : 4);
  const float* arow = W_in + (size_t)(bm * 16 + (lane & 15)) * kH;
  const __hip_bfloat16* brow = Bt + (size_t)(bn * 16 + (lane & 15)) * kH;
  f32x4 acc = {0.f, 0.f, 0.f, 0.f};
  for (int i = 0; i < 16; ++i) {
    const int kk = i * 32 + kq;
    acc = MFMA(ld8_f32(arow + kk), ld8(brow + kk), acc);
  }
  const int rm = (lane >> 4) * 4, cn = lane & 15;
  union { __hip_bfloat16 h[4]; ushort4 s; } cv;
#pragma unroll
  for (int r = 0; r < 4; ++r) cv.h[r] = __float2bfloat16(acc[r]);
  __hip_bfloat16* wd = Wall + ((size_t)mat * kH + bn * 16 + cn) * kKz + bm * 16 + rm;
  *(ushort4*)wd = cv.s;
  if (z == 0) {
#pragma unroll
    for (int r = 0; r < 4; ++r)
      Cip[(size_t)(bm * 16 + rm + r) * kH + bn * 16 + cn] = cv.h[r];
  }
}

__global__ __launch_bounds__(64) void prep_mm2(const __hip_bfloat16* Cip,
    const __hip_bfloat16* BtT, const __hip_bfloat16* BtM, __hip_bfloat16* Wall) {
  const int bm = blockIdx.x, bn = blockIdx.y, z = blockIdx.z;
  const int lane = threadIdx.x;
  const int kq = (lane >> 4) * 8;
  const __hip_bfloat16* Bt = (z == 0) ? BtT : BtM;
  const int mat = (z == 0) ? 3 : 5;
  const __hip_bfloat16* arow = Cip + (size_t)(bm * 16 + (lane & 15)) * kH;
  const __hip_bfloat16* brow = Bt + (size_t)(bn * 16 + (lane & 15)) * kH;
  f32x4 acc = {0.f, 0.f, 0.f, 0.f};
  for (int i = 0; i < 16; ++i) {
    const int kk = i * 32 + kq;
    acc = MFMA(ld8(arow + kk), ld8(brow + kk), acc);
  }
  const int rm = (lane >> 4) * 4, cn = lane & 15;
  union { __hip_bfloat16 h[4]; ushort4 s; } cv;
#pragma unroll
  for (int r = 0; r < 4; ++r) cv.h[r] = __float2bfloat16(acc[r]);
  __hip_bfloat16* wd = Wall + ((size_t)mat * kH + bn * 16 + cn) * kKz + bm * 16 + rm;
  *(ushort4*)wd = cv.s;
}

// ---------------- main persistent kernel ----------------

struct KParams {
  const __hip_bfloat16* xb;       // bf16 input [B][S][I]
  const __hip_bfloat16* Wall;     // [6][512][640] composites, [col][k]
  const __hip_bfloat16* WtOut;    // [64][512]
  const float* bias;              // [6][512]
  const float* b_out;             // [64]
  unsigned* h0a;                  // ping: [8 grp][4][512] tagged words (L2-atomic domain)
  unsigned* h0b;                  // pong
  unsigned* h0am;                 // sc1 mirror ping (LLC fallback domain)
  unsigned* h0bm;                 // sc1 mirror pong
  __hip_bfloat16* h0hist;         // [64][32][512] decode-entry snapshots
  int* arrive;                    // tail-barrier flags, 8B stride
  const int* lengths;
  float* dout;                    // [B][kOutL][C]
};

__global__ __launch_bounds__(256, 1) void rnn_main(KParams P) {
  __shared__ __align__(16) __hip_bfloat16 zs[16][kKz + kZPad];  // 20,736 B
  __shared__ __align__(16) float outLDS[6][4][16][4];           // [mat][wave][col][b]
  __shared__ int len_s[kBpG];
  __shared__ int xcc_s;
  __shared__ int flag_s;

  const int tid = threadIdx.x;
  const int lane = tid & 63, wave = tid >> 6;
  const int kq = (lane >> 4) * 8;
  const int g    = blockIdx.x & 7;       // group id (blockIdx round-robin)
  const int slot = blockIdx.x >> 3;      // [0,32): column slice within group
  const int jn   = slot * kJPW + (lane & 15);
  const int bg0  = kBpG * g;             // first global batch of group

  if (tid == 0) {
    unsigned xcc;
    asm volatile("s_getreg_b32 %0, hwreg(HW_REG_XCC_ID)" : "=s"(xcc));
    xcc_s = (int)(xcc & 7u);
    flag_s = 0;
  }

  // ---- weight preload: wave w owns K in [w*160,(w+1)*160); 6 mats x 5 iters ----
  bf16x8 wreg[6][5];
#pragma unroll
  for (int m = 0; m < 6; ++m)
#pragma unroll
    for (int i = 0; i < 5; ++i)
      wreg[m][i] = ld8(P.Wall + ((size_t)m * kH + jn) * kKz + wave * 160 + i * 32 + kq);

  if (tid < kBpG) len_s[tid] = P.lengths[bg0 + tid];

  // zero zs rows 4..15 (unused MFMA A-rows must stay zero)
  for (int idx = tid; idx < 12 * (kKz + kZPad) / 2; idx += 256)
    ((unsigned*)&zs[4][0])[idx] = 0u;

  // stage x(0)
  if (tid < 64) {
    const int b = tid >> 4, seg = tid & 15;
    *(u32x4*)&zs[b][kH + seg * 8] =
        *(const u32x4*)(P.xb + ((size_t)(bg0 + b) * kS + 0) * kI + seg * 8);
  }

  float bufr[2][kBufD];
#pragma unroll
  for (int u = 0; u < 2; ++u)
#pragma unroll
    for (int d = 0; d < kBufD; ++d) bufr[u][d] = 0.f;

  const int eb = tid >> 3, epr = tid & 7;        // epilogue geometry (tid<32)
  const unsigned o0 = (unsigned)tid * 16u;
  const unsigned o1 = o0 + 4096u;
  unsigned* const h0a_g  = P.h0a  + (size_t)g * kWrd;
  unsigned* const h0b_g  = P.h0b  + (size_t)g * kWrd;
  unsigned* const h0am_g = P.h0am + (size_t)g * kWrd;
  unsigned* const h0bm_g = P.h0bm + (size_t)g * kWrd;

  bool coh = false;     // decided after the t=1 poll; gates the atomic path
  bool fastok = true;   // sticky: atomic tier self-disables on first timeout
  bool dead = false;    // sticky: LLC poll cap hit -> never block again

  for (int t = 0; t < kSteps; ++t) {
    const unsigned* h0r  = (t & 1) ? h0b_g  : h0a_g;
    const unsigned* h0rm = (t & 1) ? h0bm_g : h0am_g;
    unsigned*       h0w  = (t & 1) ? h0a_g  : h0b_g;
    unsigned*       h0wm = (t & 1) ? h0am_g : h0bm_g;
    const unsigned tga = ((unsigned)t) << 16;
    u32x4 c0, c1;
    bool got = false;

    // ---- tier 1 (coh, t>=2): fused detect+fetch via L2 atomics.
    //      atomic_or(0) sc0 executes AT the shared L2 — no staleness window.
    //      NOTE: global_* offset imm is 13-bit signed => second half via o1.
    if (t >= 2 && coh && fastok) {
      const unsigned long long zq = 0ull;
      unsigned long long q0, q1, q2, q3;
      for (int spin = 0; spin < kFastSpin; ++spin) {
        asm volatile(
            "global_atomic_or_x2 %0, %4, %6, %7 sc0\n\t"
            "global_atomic_or_x2 %1, %4, %6, %7 offset:8 sc0\n\t"
            "global_atomic_or_x2 %2, %5, %6, %7 sc0\n\t"
            "global_atomic_or_x2 %3, %5, %6, %7 offset:8 sc0\n\t"
            "s_waitcnt vmcnt(0)"
            : "=&v"(q0), "=&v"(q1), "=&v"(q2), "=&v"(q3)
            : "v"(o0), "v"(o1), "v"(zq), "s"(h0r)
            : "memory");
        const unsigned w0 = (unsigned)q0, w1 = (unsigned)(q0 >> 32);
        const unsigned w2 = (unsigned)q1, w3 = (unsigned)(q1 >> 32);
        const unsigned w4 = (unsigned)q2, w5 = (unsigned)(q2 >> 32);
        const unsigned w6 = (unsigned)q3, w7 = (unsigned)(q3 >> 32);
        const unsigned bad = (w0 ^ tga) | (w1 ^ tga) | (w2 ^ tga) | (w3 ^ tga) |
                             (w4 ^ tga) | (w5 ^ tga) | (w6 ^ tga) | (w7 ^ tga);
        if ((bad & kTagMask) == 0) {
          c0.x = w0; c0.y = w1; c0.z = w2; c0.w = w3;
          c1.x = w4; c1.y = w5; c1.z = w6; c1.w = w7;
          got = true;
          break;
        }
      }
      if (!got) fastok = false;   // pay the probe cost exactly once
    }
    // ---- tier 2: LLC poll (verified R12 semantics), capped. In coh mode the
    //      atomic publishes aren't LLC-visible => read the sc1 MIRROR. ----
    if (!got) {
      const unsigned* pr = (coh && t >= 2) ? h0rm : h0r;
      for (unsigned spin = 0;; ++spin) {
        asm volatile(
            "global_load_dwordx4 %0, %2, %4 sc0 sc1\n\t"
            "global_load_dwordx4 %1, %3, %4 sc0 sc1\n\t"
            "s_waitcnt vmcnt(0)"
            : "=&v"(c0), "=&v"(c1)
            : "v"(o0), "v"(o1), "s"(pr)
            : "memory");
        const unsigned bad = (c0.x ^ tga) | (c0.y ^ tga) | (c0.z ^ tga) | (c0.w ^ tga) |
                             (c1.x ^ tga) | (c1.y ^ tga) | (c1.z ^ tga) | (c1.w ^ tga);
        if ((bad & kTagMask) == 0) break;
        if (dead || spin > kSpinCap) { dead = true; break; }
        __builtin_amdgcn_s_sleep(1);
      }
    }
    if (t == 1) {
      // topology verdict: ALL slab words must carry MY XCC => group-local L2.
      const unsigned myx = ((unsigned)xcc_s) << 25;   // ordered by t=0 barriers
      const unsigned d = (c0.x ^ myx) | (c0.y ^ myx) | (c0.z ^ myx) | (c0.w ^ myx) |
                         (c1.x ^ myx) | (c1.y ^ myx) | (c1.z ^ myx) | (c1.w ^ myx);
      if (d & kXccMask) flag_s = 1;      // benign race: writers all store 1
    }
    { // unpack: word w of slab -> (b = w>>9, col = w&511)
      const int bb = tid >> 7, c4 = (tid & 127) * 4;
      *(uint2*)&zs[bb][c4] =
          make_uint2((c0.x & 0xffffu) | (c0.y << 16), (c0.z & 0xffffu) | (c0.w << 16));
      *(uint2*)&zs[2 + bb][c4] =
          make_uint2((c1.x & 0xffffu) | (c1.y << 16), (c1.z & 0xffffu) | (c1.w << 16));
    }
    __syncthreads();
    if (t == 1) coh = (flag_s == 0);   // same 2048 words seen by all members

    // ---- GEMM: K split 4-ways across waves, weights in registers ----
    f32x4 a0 = {0.f,0.f,0.f,0.f}, a1 = {0.f,0.f,0.f,0.f}, a2 = {0.f,0.f,0.f,0.f};
    f32x4 a3 = {0.f,0.f,0.f,0.f}, a4 = {0.f,0.f,0.f,0.f}, a5 = {0.f,0.f,0.f,0.f};
    {
      const int ar = lane & 15;
      const int kb = wave * 160 + kq;
#pragma unroll
      for (int i = 0; i < 5; ++i) {
        const bf16x8 av = *(const bf16x8*)&zs[ar][kb + i * 32];
        a0 = MFMA(av, wreg[0][i], a0);
        a1 = MFMA(av, wreg[1][i], a1);
        a2 = MFMA(av, wreg[2][i], a2);
        a3 = MFMA(av, wreg[3][i], a3);
        a4 = MFMA(av, wreg[4][i], a4);
        a5 = MFMA(av, wreg[5][i], a5);
      }
    }
    // rows 0-3 (the 4 real batches) land in quarter-0 lanes: acc[r]=row r, col=lane
    if (lane < 16) {
      *(f32x4*)&outLDS[0][wave][lane][0] = a0;
      *(f32x4*)&outLDS[1][wave][lane][0] = a1;
      *(f32x4*)&outLDS[2][wave][lane][0] = a2;
      *(f32x4*)&outLDS[3][wave][lane][0] = a3;
      *(f32x4*)&outLDS[4][wave][lane][0] = a4;
      *(f32x4*)&outLDS[5][wave][lane][0] = a5;
    }
    __syncthreads();

    // ---- epilogue 1 (critical path): gates -> front -> tagged publish ----
    if (tid < 32) {
      const bool msk = (t >= kS) || (t < len_s[eb]);
      float hv2[2], tau2[2], ml2[2];
      unsigned short bits[2];
#pragma unroll
      for (int u = 0; u < 2; ++u) {
        const int cl = epr * 2 + u, j = slot * kJPW + cl;
        float s0 = outLDS[0][0][cl][eb] + outLDS[0][1][cl][eb] + outLDS[0][2][cl][eb] + outLDS[0][3][cl][eb];
        float s1 = outLDS[1][0][cl][eb] + outLDS[1][1][cl][eb] + outLDS[1][2][cl][eb] + outLDS[1][3][cl][eb];
        float s2 = outLDS[2][0][cl][eb] + outLDS[2][1][cl][eb] + outLDS[2][2][cl][eb] + outLDS[2][3][cl][eb];
        float s3 = outLDS[3][0][cl][eb] + outLDS[3][1][cl][eb] + outLDS[3][2][cl][eb] + outLDS[3][3][cl][eb];
        float s4 = outLDS[4][0][cl][eb] + outLDS[4][1][cl][eb] + outLDS[4][2][cl][eb] + outLDS[4][3][cl][eb];
        float s5 = outLDS[5][0][cl][eb] + outLDS[5][1][cl][eb] + outLDS[5][2][cl][eb] + outLDS[5][3][cl][eb];
        const float hp = s0 + P.bias[j];
        const float pv = s1 + P.bias[kH + j];
        const float ta = s2 + P.bias[2 * kH + j];
        const float tb = s3 + P.bias[3 * kH + j];
        const float ma = s4 + P.bias[4 * kH + j];
        const float mb = s5 + P.bias[5 * kH + j];
        const float hv = msk ? pv : hp;
        const float gt = msk ? tb : ta;
        const float gm = msk ? mb : ma;
        float tau = 16.f * sigm(gt);
        tau = fminf(fmaxf(tau, 1.f), 16.f);
        const float ml = sigm(gm);
        hv2[u] = hv; tau2[u] = tau; ml2[u] = ml;
        const float front = bufr[u][1] + (ml / (1.f + fabsf(tau - 1.f))) * hv;
        const __hip_bfloat16 hb = __float2bfloat16(front);
        unsigned short bt;
        __builtin_memcpy(&bt, &hb, 2);
        bits[u] = bt;
      }
      // publish: tag in 24:16, own XCC in 27:25
      const unsigned tagp = (((unsigned)(t + 1)) << 16) | (((unsigned)xcc_s) << 25);
      const unsigned long long pk =
          ((unsigned long long)(tagp | bits[1]) << 32) | (tagp | bits[0]);
      const unsigned po = (unsigned)((eb * kH + slot * kJPW + epr * 2) * 4);
      if ((t < 1) || !coh) {
        // LLC publish (read by t+1 LLC-tier polls)
        asm volatile("global_store_dwordx2 %0, %1, %2 sc0 sc1"
                     :: "v"(po), "v"(pk), "s"(h0w) : "memory");
      } else {
        // L2-atomic publish + sc1 mirror (for the LLC fallback tier)
        asm volatile("global_atomic_swap_x2 %0, %1, %2"
                     :: "v"(po), "v"(pk), "s"(h0w) : "memory");
        asm volatile("global_store_dwordx2 %0, %1, %2 sc0 sc1"
                     :: "v"(po), "v"(pk), "s"(h0wm) : "memory");
      }

      // ---- epilogue 2 (in the shadow): shift + snapshot ----
#pragma unroll
      for (int u = 0; u < 2; ++u) {
#pragma unroll
        for (int d = 1; d <= kMaxD; ++d) {
          const float w = ml2[u] / (1.f + fabsf(tau2[u] - (float)d));
          bufr[u][d - 1] = bufr[u][d] + w * hv2[u];
        }
        bufr[u][kMaxD] = 0.f;
      }
      if ((unsigned)(t - (kS - 1)) < (unsigned)kOutL) {
        const unsigned hv = ((unsigned)bits[1] << 16) | bits[0];
        unsigned* hp2 =
            (unsigned*)(P.h0hist + ((size_t)(t - (kS - 1)) * kB + (bg0 + eb)) * kH) +
            (slot * 8 + epr);
        __hip_atomic_store(hp2, hv, __ATOMIC_RELAXED, __HIP_MEMORY_SCOPE_AGENT);
      }
    } else if (wave == 1) {
      // x prefetch for t+1 (x-cols disjoint from unpack cols; ordered by next barrier)
      const int tn = t + 1;
      const int b = (tid >> 4) & 3, seg = tid & 15;
      if (tn < kS) {
        *(u32x4*)&zs[b][kH + seg * 8] =
            *(const u32x4*)(P.xb + ((size_t)(bg0 + b) * kS + tn) * kI + seg * 8);
      } else if (tn == kS) {
        const u32x4 zv = {0u, 0u, 0u, 0u};
        *(u32x4*)&zs[b][kH + seg * 8] = zv;
      }
    }
    // no trailing barrier: dataflow tags order everything within the group.
  }

  // ---- tail: one grid barrier, then decode-output GEMM on WGs 0..31 ----
  __builtin_amdgcn_s_waitcnt(0);
  __syncthreads();
  const int wg = blockIdx.x;
  if (tid == 0)
    __hip_atomic_store(&P.arrive[wg * 2], 1, __ATOMIC_RELAXED, __HIP_MEMORY_SCOPE_AGENT);
  if (tid < kNWG) {
    unsigned spin = 0;
    while (__hip_atomic_load(&P.arrive[tid * 2],
                             __ATOMIC_RELAXED, __HIP_MEMORY_SCOPE_AGENT) < 1) {
      if (++spin > kSpinCap * 16u) break;   // bounded even here
      __builtin_amdgcn_s_sleep(2);
    }
  }
  __syncthreads();
  if (wg >= 32) return;

  // dout[b][td][c] = h0hist[td][b][:] @ WtOut[c][:] + b_out[c]
  {
    const int q = lane >> 4, r = lane & 15;
    const int mrow = wg * 64 + wave * 16 + r;   // m = td*32 + b
    const char* ap = (const char*)P.h0hist + (size_t)mrow * 1024 + q * 16;
    u32x4 d0, d1, d2, d3, d4, d5, d6, d7, d8, d9, dA, dB, dC, dD, dE, dF;
    asm volatile(
        "global_load_dwordx4 %0, %16, off sc0 sc1\n\t"
        "global_load_dwordx4 %1, %16, off offset:64 sc0 sc1\n\t"
        "global_load_dwordx4 %2, %16, off offset:128 sc0 sc1\n\t"
        "global_load_dwordx4 %3, %16, off offset:192 sc0 sc1\n\t"
        "global_load_dwordx4 %4, %16, off offset:256 sc0 sc1\n\t"
        "global_load_dwordx4 %5, %16, off offset:320 sc0 sc1\n\t"
        "global_load_dwordx4 %6, %16, off offset:384 sc0 sc1\n\t"
        "global_load_dwordx4 %7, %16, off offset:448 sc0 sc1\n\t"
        "global_load_dwordx4 %8, %16, off offset:512 sc0 sc1\n\t"
        "global_load_dwordx4 %9, %16, off offset:576 sc0 sc1\n\t"
        "global_load_dwordx4 %10, %16, off offset:640 sc0 sc1\n\t"
        "global_load_dwordx4 %11, %16, off offset:704 sc0 sc1\n\t"
        "global_load_dwordx4 %12, %16, off offset:768 sc0 sc1\n\t"
        "global_load_dwordx4 %13, %16, off offset:832 sc0 sc1\n\t"
        "global_load_dwordx4 %14, %16, off offset:896 sc0 sc1\n\t"
        "global_load_dwordx4 %15, %16, off offset:960 sc0 sc1\n\t"
        "s_waitcnt vmcnt(0)"
        : "=&v"(d0), "=&v"(d1), "=&v"(d2), "=&v"(d3),
          "=&v"(d4), "=&v"(d5), "=&v"(d6), "=&v"(d7),
          "=&v"(d8), "=&v"(d9), "=&v"(dA), "=&v"(dB),
          "=&v"(dC), "=&v"(dD), "=&v"(dE), "=&v"(dF)
        : "v"(ap)
        : "memory");
    union { u32x4 u; bf16x8 v; } av[16] = {{d0},{d1},{d2},{d3},{d4},{d5},{d6},{d7},
                                           {d8},{d9},{dA},{dB},{dC},{dD},{dE},{dF}};
    f32x4 T0 = {0.f,0.f,0.f,0.f}, T1 = {0.f,0.f,0.f,0.f};
    f32x4 T2 = {0.f,0.f,0.f,0.f}, T3 = {0.f,0.f,0.f,0.f};
#pragma unroll
    for (int ik = 0; ik < 16; ++ik) {
      const int kk = ik * 32 + kq;
      const __hip_bfloat16* wb = P.WtOut + (size_t)r * kH + kk;
      T0 = MFMA(av[ik].v, ld8(wb), T0);
      T1 = MFMA(av[ik].v, ld8(wb + 16 * kH), T1);
      T2 = MFMA(av[ik].v, ld8(wb + 32 * kH), T2);
      T3 = MFMA(av[ik].v, ld8(wb + 48 * kH), T3);
    }
    f32x4 T[4] = {T0, T1, T2, T3};
#pragma unroll
    for (int ct = 0; ct < 4; ++ct) {
      const int c = ct * 16 + r;
      const float bo = P.b_out[c];
#pragma unroll
      for (int rr = 0; rr < 4; ++rr) {
        const int m = wg * 64 + wave * 16 + q * 4 + rr;
        const int b = m & 31, td = m >> 5;
        P.dout[(size_t)b * (kOutL * kC) + td * kC + c] = T[ct][rr] + bo;
      }
    }
  }
}

extern "C" void kernel_launch(void* const* d_in, const int* in_sizes, int n_in,
                              void* d_out, int out_size, void* d_ws, size_t ws_size,
                              hipStream_t stream) {
  const float* x      = (const float*)d_in[0];
  const int*   lens   = (const int*)d_in[1];
  const float* W_in   = (const float*)d_in[3];
  const float* b_in   = (const float*)d_in[4];
  const float* W_pass = (const float*)d_in[5];
  const float* b_pass = (const float*)d_in[6];
  const float* W_tau  = (const float*)d_in[7];
  const float* b_tau  = (const float*)d_in[8];
  const float* W_mem  = (const float*)d_in[9];
  const float* b_mem  = (const float*)d_in[10];
  const float* W_out  = (const float*)d_in[11];
  const float* b_out  = (const float*)d_in[12];

  char* ws = (char*)d_ws;
  size_t off = 0;
  int* arrive = (int*)(ws + off);                  off += 2048;   // 256 x 8B
  unsigned* h0a  = (unsigned*)(ws + off);          off += (size_t)kGrp * kWrd * 4;  // 64KB
  unsigned* h0b  = (unsigned*)(ws + off);          off += (size_t)kGrp * kWrd * 4;  // 64KB
  unsigned* h0am = (unsigned*)(ws + off);          off += (size_t)kGrp * kWrd * 4;  // 64KB
  unsigned* h0bm = (unsigned*)(ws + off);          off += (size_t)kGrp * kWrd * 4;  // 64KB
  float* bias = (float*)(ws + off);                off += 6 * kH * sizeof(float);
  __hip_bfloat16* WtOut = (__hip_bfloat16*)(ws + off); off += (size_t)kC * kH * 2;
  __hip_bfloat16* h0hist = (__hip_bfloat16*)(ws + off); off += (size_t)kOutL * kB * kH * 2;
  __hip_bfloat16* xb    = (__hip_bfloat16*)(ws + off); off += (size_t)kB * kS * kI * 2;
  __hip_bfloat16* Wall  = (__hip_bfloat16*)(ws + off); off += (size_t)6 * kH * kKz * 2;
  __hip_bfloat16* BtP   = (__hip_bfloat16*)(ws + off); off += (size_t)kH * kH * 2;
  __hip_bfloat16* BtT   = (__hip_bfloat16*)(ws + off); off += (size_t)kH * kH * 2;
  __hip_bfloat16* BtM   = (__hip_bfloat16*)(ws + off); off += (size_t)kH * kH * 2;
  __hip_bfloat16* Cip   = (__hip_bfloat16*)(ws + off); off += (size_t)kKz * kH * 2;

  // zero barrier flags + all four tagged h0 buffers (tag 0 == step-0 expectation)
  hipMemsetAsync(d_ws, 0, 2048 + 4 * (size_t)kGrp * kWrd * 4, stream);

  prep_cast<<<512, 256, 0, stream>>>(x, W_in, W_pass, W_tau, W_mem, W_out,
                                     xb, Wall, BtP, BtT, BtM, WtOut);
  prep_bias<<<1, 512, 0, stream>>>(b_in, b_pass, b_tau, b_mem, W_pass, W_tau, W_mem, bias);
  prep_mm1<<<dim3(40, 32, 3), 64, 0, stream>>>(W_in, BtP, BtT, BtM, Wall, Cip);
  prep_mm2<<<dim3(40, 32, 2), 64, 0, stream>>>(Cip, BtT, BtM, Wall);

  KParams P;
  P.xb = xb; P.Wall = Wall; P.WtOut = WtOut; P.bias = bias; P.b_out = b_out;
  P.h0a = h0a; P.h0b = h0b; P.h0am = h0am; P.h0bm = h0bm;
  P.h0hist = h0hist; P.arrive = arrive;
  P.lengths = lens; P.dout = (float*)d_out;

  rnn_main<<<dim3(kNWG), dim3(256), 0, stream>>>(P);
}

// Round 8
// 1737.541 us; speedup vs baseline: 3.2880x; 3.2880x over previous
//
#include <hip/hip_runtime.h>
#include <hip/hip_bf16.h>

// DelayRNN on MI355X — Round 22: plain-store publish into the shared XCD L2.
// Evidence table (R18/R19/R21): sc0 store = write-around, never updates the
// local L2 line (stale polls, R18 garbage); sc0+sc1 store = LLC write +
// L2 invalidate (R19 works, but every step pays ~3.4us LLC RTT); atomics =
// memory-side execution (R21: 5.5GB TCC writes, 4x slower). The untested
// cheap cell: a PLAIN (no-flags) store is a normal write-back L2 allocation
// on the write-through-L1 CDNA path -> it UPDATES the line that same-XCD
// sc0 polls read. Visibility then = store-to-L2 + L2-hit poll (~0.3us).
//   * coherent publish: plain store to main slab + sc0 sc1 MIRROR store
//     (keeps the LLC fallback viable).
//   * tier-1 poll: R19's plain sc0 loads (L1-bypass, L2-hit), cap 256,
//     sticky self-disable -> tier-2 capped LLC poll on the mirror.
//   * polls are LOADS only — R21's lesson: never poll with atomics.
// Everything else (weights in 120 VGPRs, 8 groups x 4 batches verified
// same-XCD in-band at t=1, 8KB slab, 319 steps, tail decode GEMM) = R19.

constexpr int kB    = 32;
constexpr int kS    = 256;
constexpr int kI    = 128;
constexpr int kH    = 512;
constexpr int kC    = 64;
constexpr int kOutL = 64;
constexpr int kMaxD = 16;
constexpr int kBufD = 17;
constexpr int kNWG  = 256;
constexpr int kJPW  = 16;
constexpr int kGrp  = 8;                 // groups (== XCDs, verified in-band)
constexpr int kBpG  = kB / kGrp;         // 4 batches per group
constexpr int kWrd  = kBpG * kH;         // 2048 tagged u32 per group slab (8KB)
constexpr int kSteps = kS + kOutL - 1;   // 319: last needed publish is t=318
constexpr int kKz   = kH + kI;           // 640
constexpr int kZPad = 8;                 // zs row stride 648 elem (1296 B)
constexpr int      kFastSpin = 256;      // L2 probe rounds (~0.15us each)
constexpr unsigned kSpinCap  = 131072;   // LLC poll cap — wedge-proof
constexpr unsigned kTagMask  = 0x01ff0000u;  // tag bits 24:16 (tags <= 319)
constexpr unsigned kXccMask  = 0x0e000000u;  // XCC_ID bits 27:25

typedef __bf16 bf16x8 __attribute__((ext_vector_type(8)));
typedef float  f32x4  __attribute__((ext_vector_type(4)));
typedef unsigned int u32x4 __attribute__((ext_vector_type(4)));

__device__ __forceinline__ f32x4 MFMA(bf16x8 a, bf16x8 b, f32x4 c) {
  return __builtin_amdgcn_mfma_f32_16x16x32_bf16(a, b, c, 0, 0, 0);
}
__device__ __forceinline__ bf16x8 ld8(const __hip_bfloat16* p) {
  return *reinterpret_cast<const bf16x8*>(p);
}
__device__ __forceinline__ bf16x8 ld8_f32(const float* p) {
  float4 a = *(const float4*)p, b = *(const float4*)(p + 4);
  union { __hip_bfloat16 h[8]; bf16x8 v; } c;
  c.h[0] = __float2bfloat16(a.x); c.h[1] = __float2bfloat16(a.y);
  c.h[2] = __float2bfloat16(a.z); c.h[3] = __float2bfloat16(a.w);
  c.h[4] = __float2bfloat16(b.x); c.h[5] = __float2bfloat16(b.y);
  c.h[6] = __float2bfloat16(b.z); c.h[7] = __float2bfloat16(b.w);
  return c.v;
}
__device__ __forceinline__ float sigm(float x) { return 1.0f / (1.0f + __expf(-x)); }

// ---------------- prep kernels (validated R2-R12, unchanged) ----------------

__global__ void prep_cast(const float* x, const float* W_in, const float* W_pass,
                          const float* W_tau, const float* W_mem, const float* W_out,
                          __hip_bfloat16* xb, __hip_bfloat16* Wall, __hip_bfloat16* BtP,
                          __hip_bfloat16* BtT, __hip_bfloat16* BtM, __hip_bfloat16* WtOut) {
  const int tid = blockIdx.x * blockDim.x + threadIdx.x;
  const int nth = gridDim.x * blockDim.x;
  for (int i = tid; i < kB * kS * kI; i += nth) xb[i] = __float2bfloat16(x[i]);
  for (int i = tid; i < kH * kKz; i += nth) {
    int j = i / kKz, k = i - j * kKz;
    Wall[i] = __float2bfloat16(W_in[k * kH + j]);
  }
  for (int i = tid; i < kH * kH; i += nth) {
    int j = i >> 9, k = i & 511;
    BtP[i] = __float2bfloat16(W_pass[k * kH + j]);
    BtT[i] = __float2bfloat16(W_tau[k * kH + j]);
    BtM[i] = __float2bfloat16(W_mem[k * kH + j]);
  }
  for (int i = tid; i < kC * kH; i += nth) {
    int c = i >> 9, k = i & 511;
    WtOut[i] = __float2bfloat16(W_out[k * kC + c]);
  }
}

__global__ void prep_bias(const float* b_in, const float* b_pass, const float* b_tau,
                          const float* b_mem, const float* W_pass, const float* W_tau,
                          const float* W_mem, float* bias) {
  __shared__ float bp_s[kH];
  const int j = threadIdx.x;
  float s1 = 0.f, s2 = 0.f, s3 = 0.f;
  for (int k = 0; k < kH; ++k) {
    float bi = b_in[k];
    s1 += bi * W_pass[k * kH + j];
    s2 += bi * W_tau[k * kH + j];
    s3 += bi * W_mem[k * kH + j];
  }
  float bP = s1 + b_pass[j];
  bias[j]          = b_in[j];
  bias[kH + j]     = bP;
  bias[2 * kH + j] = s2 + b_tau[j];
  bias[4 * kH + j] = s3 + b_mem[j];
  bp_s[j] = bP;
  __syncthreads();
  float s4 = 0.f, s5 = 0.f;
  for (int k = 0; k < kH; ++k) {
    float v = bp_s[k];
    s4 += v * W_tau[k * kH + j];
    s5 += v * W_mem[k * kH + j];
  }
  bias[3 * kH + j] = s4 + b_tau[j];
  bias[5 * kH + j] = s5 + b_mem[j];
}

__global__ __launch_bounds__(64) void prep_mm1(const float* W_in, const __hip_bfloat16* BtP,
    const __hip_bfloat16* BtT, const __hip_bfloat16* BtM,
    __hip_bfloat16* Wall, __hip_bfloat16* Cip) {
  const int bm = blockIdx.x, bn = blockIdx.y, z = blockIdx.z;
  const int lane = threadIdx.x;
  const int kq = (lane >> 4) * 8;
  const __hip_bfloat16* Bt = (z == 0) ? BtP : (z == 1 ? BtT : BtM);
  const int mat = (z == 0) ? 1 : (z == 1 ? 2 : 4);
  const float* arow = W_in + (size_t)(bm * 16 + (lane & 15)) * kH;
  const __hip_bfloat16* brow = Bt + (size_t)(bn * 16 + (lane & 15)) * kH;
  f32x4 acc = {0.f, 0.f, 0.f, 0.f};
  for (int i = 0; i < 16; ++i) {
    const int kk = i * 32 + kq;
    acc = MFMA(ld8_f32(arow + kk), ld8(brow + kk), acc);
  }
  const int rm = (lane >> 4) * 4, cn = lane & 15;
  union { __hip_bfloat16 h[4]; ushort4 s; } cv;
#pragma unroll
  for (int r = 0; r < 4; ++r) cv.h[r] = __float2bfloat16(acc[r]);
  __hip_bfloat16* wd = Wall + ((size_t)mat * kH + bn * 16 + cn) * kKz + bm * 16 + rm;
  *(ushort4*)wd = cv.s;
  if (z == 0) {
#pragma unroll
    for (int r = 0; r < 4; ++r)
      Cip[(size_t)(bm * 16 + rm + r) * kH + bn * 16 + cn] = cv.h[r];
  }
}

__global__ __launch_bounds__(64) void prep_mm2(const __hip_bfloat16* Cip,
    const __hip_bfloat16* BtT, const __hip_bfloat16* BtM, __hip_bfloat16* Wall) {
  const int bm = blockIdx.x, bn = blockIdx.y, z = blockIdx.z;
  const int lane = threadIdx.x;
  const int kq = (lane >> 4) * 8;
  const __hip_bfloat16* Bt = (z == 0) ? BtT : BtM;
  const int mat = (z == 0) ? 3 : 5;
  const __hip_bfloat16* arow = Cip + (size_t)(bm * 16 + (lane & 15)) * kH;
  const __hip_bfloat16* brow = Bt + (size_t)(bn * 16 + (lane & 15)) * kH;
  f32x4 acc = {0.f, 0.f, 0.f, 0.f};
  for (int i = 0; i < 16; ++i) {
    const int kk = i * 32 + kq;
    acc = MFMA(ld8(arow + kk), ld8(brow + kk), acc);
  }
  const int rm = (lane >> 4) * 4, cn = lane & 15;
  union { __hip_bfloat16 h[4]; ushort4 s; } cv;
#pragma unroll
  for (int r = 0; r < 4; ++r) cv.h[r] = __float2bfloat16(acc[r]);
  __hip_bfloat16* wd = Wall + ((size_t)mat * kH + bn * 16 + cn) * kKz + bm * 16 + rm;
  *(ushort4*)wd = cv.s;
}

// ---------------- main persistent kernel ----------------

struct KParams {
  const __hip_bfloat16* xb;       // bf16 input [B][S][I]
  const __hip_bfloat16* Wall;     // [6][512][640] composites, [col][k]
  const __hip_bfloat16* WtOut;    // [64][512]
  const float* bias;              // [6][512]
  const float* b_out;             // [64]
  unsigned* h0a;                  // ping: [8 grp][4][512] tagged words (L2 domain)
  unsigned* h0b;                  // pong
  unsigned* h0am;                 // sc1 mirror ping (LLC fallback domain)
  unsigned* h0bm;                 // sc1 mirror pong
  __hip_bfloat16* h0hist;         // [64][32][512] decode-entry snapshots
  int* arrive;                    // tail-barrier flags, 8B stride
  const int* lengths;
  float* dout;                    // [B][kOutL][C]
};

__global__ __launch_bounds__(256, 1) void rnn_main(KParams P) {
  __shared__ __align__(16) __hip_bfloat16 zs[16][kKz + kZPad];  // 20,736 B
  __shared__ __align__(16) float outLDS[6][4][16][4];           // [mat][wave][col][b]
  __shared__ int len_s[kBpG];
  __shared__ int xcc_s;
  __shared__ int flag_s;

  const int tid = threadIdx.x;
  const int lane = tid & 63, wave = tid >> 6;
  const int kq = (lane >> 4) * 8;
  const int g    = blockIdx.x & 7;       // group id (blockIdx round-robin)
  const int slot = blockIdx.x >> 3;      // [0,32): column slice within group
  const int jn   = slot * kJPW + (lane & 15);
  const int bg0  = kBpG * g;             // first global batch of group

  if (tid == 0) {
    unsigned xcc;
    asm volatile("s_getreg_b32 %0, hwreg(HW_REG_XCC_ID)" : "=s"(xcc));
    xcc_s = (int)(xcc & 7u);
    flag_s = 0;
  }

  // ---- weight preload: wave w owns K in [w*160,(w+1)*160); 6 mats x 5 iters ----
  bf16x8 wreg[6][5];
#pragma unroll
  for (int m = 0; m < 6; ++m)
#pragma unroll
    for (int i = 0; i < 5; ++i)
      wreg[m][i] = ld8(P.Wall + ((size_t)m * kH + jn) * kKz + wave * 160 + i * 32 + kq);

  if (tid < kBpG) len_s[tid] = P.lengths[bg0 + tid];

  // zero zs rows 4..15 (unused MFMA A-rows must stay zero)
  for (int idx = tid; idx < 12 * (kKz + kZPad) / 2; idx += 256)
    ((unsigned*)&zs[4][0])[idx] = 0u;

  // stage x(0)
  if (tid < 64) {
    const int b = tid >> 4, seg = tid & 15;
    *(u32x4*)&zs[b][kH + seg * 8] =
        *(const u32x4*)(P.xb + ((size_t)(bg0 + b) * kS + 0) * kI + seg * 8);
  }

  float bufr[2][kBufD];
#pragma unroll
  for (int u = 0; u < 2; ++u)
#pragma unroll
    for (int d = 0; d < kBufD; ++d) bufr[u][d] = 0.f;

  const int eb = tid >> 3, epr = tid & 7;        // epilogue geometry (tid<32)
  const unsigned o0 = (unsigned)tid * 16u;
  const unsigned o1 = o0 + 4096u;
  unsigned* const h0a_g  = P.h0a  + (size_t)g * kWrd;
  unsigned* const h0b_g  = P.h0b  + (size_t)g * kWrd;
  unsigned* const h0am_g = P.h0am + (size_t)g * kWrd;
  unsigned* const h0bm_g = P.h0bm + (size_t)g * kWrd;

  bool coh = false;     // decided after the t=1 poll; gates the fast path
  bool fastok = true;   // sticky: fast tier self-disables on first timeout
  bool dead = false;    // sticky: LLC poll cap hit -> never block again

  for (int t = 0; t < kSteps; ++t) {
    const unsigned* h0r  = (t & 1) ? h0b_g  : h0a_g;
    const unsigned* h0rm = (t & 1) ? h0bm_g : h0am_g;
    unsigned*       h0w  = (t & 1) ? h0a_g  : h0b_g;
    unsigned*       h0wm = (t & 1) ? h0am_g : h0bm_g;
    const unsigned tga = ((unsigned)t) << 16;
    u32x4 c0, c1;
    bool got = false;

    // ---- tier 1 (coh, t>=2): sc0 (L1-bypass) probes of the shared L2.
    //      Publishes are PLAIN stores => they UPDATE the L2 line in place;
    //      probes are L2 hits (~0.15us/round), read-only (R21 lesson). ----
    if (t >= 2 && coh && fastok) {
      for (int spin = 0; spin < kFastSpin; ++spin) {
        asm volatile(
            "global_load_dwordx4 %0, %2, %4 sc0\n\t"
            "global_load_dwordx4 %1, %3, %4 sc0\n\t"
            "s_waitcnt vmcnt(0)"
            : "=&v"(c0), "=&v"(c1)
            : "v"(o0), "v"(o1), "s"(h0r)
            : "memory");
        const unsigned bad = (c0.x ^ tga) | (c0.y ^ tga) | (c0.z ^ tga) | (c0.w ^ tga) |
                             (c1.x ^ tga) | (c1.y ^ tga) | (c1.z ^ tga) | (c1.w ^ tga);
        if ((bad & kTagMask) == 0) { got = true; break; }
      }
      if (!got) fastok = false;   // pay the probe cost exactly once
    }
    // ---- tier 2: LLC poll (verified R12/R19 semantics), capped. In coh mode
    //      plain-store publishes may not be LLC-visible => read the MIRROR. ----
    if (!got) {
      const unsigned* pr = (coh && t >= 2) ? h0rm : h0r;
      for (unsigned spin = 0;; ++spin) {
        asm volatile(
            "global_load_dwordx4 %0, %2, %4 sc0 sc1\n\t"
            "global_load_dwordx4 %1, %3, %4 sc0 sc1\n\t"
            "s_waitcnt vmcnt(0)"
            : "=&v"(c0), "=&v"(c1)
            : "v"(o0), "v"(o1), "s"(pr)
            : "memory");
        const unsigned bad = (c0.x ^ tga) | (c0.y ^ tga) | (c0.z ^ tga) | (c0.w ^ tga) |
                             (c1.x ^ tga) | (c1.y ^ tga) | (c1.z ^ tga) | (c1.w ^ tga);
        if ((bad & kTagMask) == 0) break;
        if (dead || spin > kSpinCap) { dead = true; break; }
        __builtin_amdgcn_s_sleep(1);
      }
    }
    if (t == 1) {
      // topology verdict: ALL slab words must carry MY XCC => group-local L2.
      const unsigned myx = ((unsigned)xcc_s) << 25;   // ordered by t=0 barriers
      const unsigned d = (c0.x ^ myx) | (c0.y ^ myx) | (c0.z ^ myx) | (c0.w ^ myx) |
                         (c1.x ^ myx) | (c1.y ^ myx) | (c1.z ^ myx) | (c1.w ^ myx);
      if (d & kXccMask) flag_s = 1;      // benign race: writers all store 1
    }
    { // unpack: word w of slab -> (b = w>>9, col = w&511)
      const int bb = tid >> 7, c4 = (tid & 127) * 4;
      *(uint2*)&zs[bb][c4] =
          make_uint2((c0.x & 0xffffu) | (c0.y << 16), (c0.z & 0xffffu) | (c0.w << 16));
      *(uint2*)&zs[2 + bb][c4] =
          make_uint2((c1.x & 0xffffu) | (c1.y << 16), (c1.z & 0xffffu) | (c1.w << 16));
    }
    __syncthreads();
    if (t == 1) coh = (flag_s == 0);   // same 2048 words seen by all members

    // ---- GEMM: K split 4-ways across waves, weights in registers ----
    f32x4 a0 = {0.f,0.f,0.f,0.f}, a1 = {0.f,0.f,0.f,0.f}, a2 = {0.f,0.f,0.f,0.f};
    f32x4 a3 = {0.f,0.f,0.f,0.f}, a4 = {0.f,0.f,0.f,0.f}, a5 = {0.f,0.f,0.f,0.f};
    {
      const int ar = lane & 15;
      const int kb = wave * 160 + kq;
#pragma unroll
      for (int i = 0; i < 5; ++i) {
        const bf16x8 av = *(const bf16x8*)&zs[ar][kb + i * 32];
        a0 = MFMA(av, wreg[0][i], a0);
        a1 = MFMA(av, wreg[1][i], a1);
        a2 = MFMA(av, wreg[2][i], a2);
        a3 = MFMA(av, wreg[3][i], a3);
        a4 = MFMA(av, wreg[4][i], a4);
        a5 = MFMA(av, wreg[5][i], a5);
      }
    }
    // rows 0-3 (the 4 real batches) land in quarter-0 lanes: acc[r]=row r, col=lane
    if (lane < 16) {
      *(f32x4*)&outLDS[0][wave][lane][0] = a0;
      *(f32x4*)&outLDS[1][wave][lane][0] = a1;
      *(f32x4*)&outLDS[2][wave][lane][0] = a2;
      *(f32x4*)&outLDS[3][wave][lane][0] = a3;
      *(f32x4*)&outLDS[4][wave][lane][0] = a4;
      *(f32x4*)&outLDS[5][wave][lane][0] = a5;
    }
    __syncthreads();

    // ---- epilogue 1 (critical path): gates -> front -> tagged publish ----
    if (tid < 32) {
      const bool msk = (t >= kS) || (t < len_s[eb]);
      float hv2[2], tau2[2], ml2[2];
      unsigned short bits[2];
#pragma unroll
      for (int u = 0; u < 2; ++u) {
        const int cl = epr * 2 + u, j = slot * kJPW + cl;
        float s0 = outLDS[0][0][cl][eb] + outLDS[0][1][cl][eb] + outLDS[0][2][cl][eb] + outLDS[0][3][cl][eb];
        float s1 = outLDS[1][0][cl][eb] + outLDS[1][1][cl][eb] + outLDS[1][2][cl][eb] + outLDS[1][3][cl][eb];
        float s2 = outLDS[2][0][cl][eb] + outLDS[2][1][cl][eb] + outLDS[2][2][cl][eb] + outLDS[2][3][cl][eb];
        float s3 = outLDS[3][0][cl][eb] + outLDS[3][1][cl][eb] + outLDS[3][2][cl][eb] + outLDS[3][3][cl][eb];
        float s4 = outLDS[4][0][cl][eb] + outLDS[4][1][cl][eb] + outLDS[4][2][cl][eb] + outLDS[4][3][cl][eb];
        float s5 = outLDS[5][0][cl][eb] + outLDS[5][1][cl][eb] + outLDS[5][2][cl][eb] + outLDS[5][3][cl][eb];
        const float hp = s0 + P.bias[j];
        const float pv = s1 + P.bias[kH + j];
        const float ta = s2 + P.bias[2 * kH + j];
        const float tb = s3 + P.bias[3 * kH + j];
        const float ma = s4 + P.bias[4 * kH + j];
        const float mb = s5 + P.bias[5 * kH + j];
        const float hv = msk ? pv : hp;
        const float gt = msk ? tb : ta;
        const float gm = msk ? mb : ma;
        float tau = 16.f * sigm(gt);
        tau = fminf(fmaxf(tau, 1.f), 16.f);
        const float ml = sigm(gm);
        hv2[u] = hv; tau2[u] = tau; ml2[u] = ml;
        const float front = bufr[u][1] + (ml / (1.f + fabsf(tau - 1.f))) * hv;
        const __hip_bfloat16 hb = __float2bfloat16(front);
        unsigned short bt;
        __builtin_memcpy(&bt, &hb, 2);
        bits[u] = bt;
      }
      // publish: tag in 24:16, own XCC in 27:25
      const unsigned tagp = (((unsigned)(t + 1)) << 16) | (((unsigned)xcc_s) << 25);
      const unsigned long long pk =
          ((unsigned long long)(tagp | bits[1]) << 32) | (tagp | bits[0]);
      const unsigned po = (unsigned)((eb * kH + slot * kJPW + epr * 2) * 4);
      if ((t < 1) || !coh) {
        // LLC publish (read by t+1 LLC-tier polls on the main slab)
        asm volatile("global_store_dwordx2 %0, %1, %2 sc0 sc1"
                     :: "v"(po), "v"(pk), "s"(h0w) : "memory");
      } else {
        // PLAIN store: normal write-back allocation in the shared XCD L2 —
        // updates the line tier-1's sc0 probes are reading. Mirror keeps
        // the LLC fallback viable.
        asm volatile("global_store_dwordx2 %0, %1, %2"
                     :: "v"(po), "v"(pk), "s"(h0w) : "memory");
        asm volatile("global_store_dwordx2 %0, %1, %2 sc0 sc1"
                     :: "v"(po), "v"(pk), "s"(h0wm) : "memory");
      }

      // ---- epilogue 2 (in the shadow): shift + snapshot ----
#pragma unroll
      for (int u = 0; u < 2; ++u) {
#pragma unroll
        for (int d = 1; d <= kMaxD; ++d) {
          const float w = ml2[u] / (1.f + fabsf(tau2[u] - (float)d));
          bufr[u][d - 1] = bufr[u][d] + w * hv2[u];
        }
        bufr[u][kMaxD] = 0.f;
      }
      if ((unsigned)(t - (kS - 1)) < (unsigned)kOutL) {
        const unsigned hv = ((unsigned)bits[1] << 16) | bits[0];
        unsigned* hp2 =
            (unsigned*)(P.h0hist + ((size_t)(t - (kS - 1)) * kB + (bg0 + eb)) * kH) +
            (slot * 8 + epr);
        __hip_atomic_store(hp2, hv, __ATOMIC_RELAXED, __HIP_MEMORY_SCOPE_AGENT);
      }
    } else if (wave == 1) {
      // x prefetch for t+1 (x-cols disjoint from unpack cols; ordered by next barrier)
      const int tn = t + 1;
      const int b = (tid >> 4) & 3, seg = tid & 15;
      if (tn < kS) {
        *(u32x4*)&zs[b][kH + seg * 8] =
            *(const u32x4*)(P.xb + ((size_t)(bg0 + b) * kS + tn) * kI + seg * 8);
      } else if (tn == kS) {
        const u32x4 zv = {0u, 0u, 0u, 0u};
        *(u32x4*)&zs[b][kH + seg * 8] = zv;
      }
    }
    // no trailing barrier: dataflow tags order everything within the group.
  }

  // ---- tail: one grid barrier, then decode-output GEMM on WGs 0..31 ----
  __builtin_amdgcn_s_waitcnt(0);
  __syncthreads();
  const int wg = blockIdx.x;
  if (tid == 0)
    __hip_atomic_store(&P.arrive[wg * 2], 1, __ATOMIC_RELAXED, __HIP_MEMORY_SCOPE_AGENT);
  if (tid < kNWG) {
    unsigned spin = 0;
    while (__hip_atomic_load(&P.arrive[tid * 2],
                             __ATOMIC_RELAXED, __HIP_MEMORY_SCOPE_AGENT) < 1) {
      if (++spin > kSpinCap * 16u) break;   // bounded even here
      __builtin_amdgcn_s_sleep(2);
    }
  }
  __syncthreads();
  if (wg >= 32) return;

  // dout[b][td][c] = h0hist[td][b][:] @ WtOut[c][:] + b_out[c]
  {
    const int q = lane >> 4, r = lane & 15;
    const int mrow = wg * 64 + wave * 16 + r;   // m = td*32 + b
    const char* ap = (const char*)P.h0hist + (size_t)mrow * 1024 + q * 16;
    u32x4 d0, d1, d2, d3, d4, d5, d6, d7, d8, d9, dA, dB, dC, dD, dE, dF;
    asm volatile(
        "global_load_dwordx4 %0, %16, off sc0 sc1\n\t"
        "global_load_dwordx4 %1, %16, off offset:64 sc0 sc1\n\t"
        "global_load_dwordx4 %2, %16, off offset:128 sc0 sc1\n\t"
        "global_load_dwordx4 %3, %16, off offset:192 sc0 sc1\n\t"
        "global_load_dwordx4 %4, %16, off offset:256 sc0 sc1\n\t"
        "global_load_dwordx4 %5, %16, off offset:320 sc0 sc1\n\t"
        "global_load_dwordx4 %6, %16, off offset:384 sc0 sc1\n\t"
        "global_load_dwordx4 %7, %16, off offset:448 sc0 sc1\n\t"
        "global_load_dwordx4 %8, %16, off offset:512 sc0 sc1\n\t"
        "global_load_dwordx4 %9, %16, off offset:576 sc0 sc1\n\t"
        "global_load_dwordx4 %10, %16, off offset:640 sc0 sc1\n\t"
        "global_load_dwordx4 %11, %16, off offset:704 sc0 sc1\n\t"
        "global_load_dwordx4 %12, %16, off offset:768 sc0 sc1\n\t"
        "global_load_dwordx4 %13, %16, off offset:832 sc0 sc1\n\t"
        "global_load_dwordx4 %14, %16, off offset:896 sc0 sc1\n\t"
        "global_load_dwordx4 %15, %16, off offset:960 sc0 sc1\n\t"
        "s_waitcnt vmcnt(0)"
        : "=&v"(d0), "=&v"(d1), "=&v"(d2), "=&v"(d3),
          "=&v"(d4), "=&v"(d5), "=&v"(d6), "=&v"(d7),
          "=&v"(d8), "=&v"(d9), "=&v"(dA), "=&v"(dB),
          "=&v"(dC), "=&v"(dD), "=&v"(dE), "=&v"(dF)
        : "v"(ap)
        : "memory");
    union { u32x4 u; bf16x8 v; } av[16] = {{d0},{d1},{d2},{d3},{d4},{d5},{d6},{d7},
                                           {d8},{d9},{dA},{dB},{dC},{dD},{dE},{dF}};
    f32x4 T0 = {0.f,0.f,0.f,0.f}, T1 = {0.f,0.f,0.f,0.f};
    f32x4 T2 = {0.f,0.f,0.f,0.f}, T3 = {0.f,0.f,0.f,0.f};
#pragma unroll
    for (int ik = 0; ik < 16; ++ik) {
      const int kk = ik * 32 + kq;
      const __hip_bfloat16* wb = P.WtOut + (size_t)r * kH + kk;
      T0 = MFMA(av[ik].v, ld8(wb), T0);
      T1 = MFMA(av[ik].v, ld8(wb + 16 * kH), T1);
      T2 = MFMA(av[ik].v, ld8(wb + 32 * kH), T2);
      T3 = MFMA(av[ik].v, ld8(wb + 48 * kH), T3);
    }
    f32x4 T[4] = {T0, T1, T2, T3};
#pragma unroll
    for (int ct = 0; ct < 4; ++ct) {
      const int c = ct * 16 + r;
      const float bo = P.b_out[c];
#pragma unroll
      for (int rr = 0; rr < 4; ++rr) {
        const int m = wg * 64 + wave * 16 + q * 4 + rr;
        const int b = m & 31, td = m >> 5;
        P.dout[(size_t)b * (kOutL * kC) + td * kC + c] = T[ct][rr] + bo;
      }
    }
  }
}

extern "C" void kernel_launch(void* const* d_in, const int* in_sizes, int n_in,
                              void* d_out, int out_size, void* d_ws, size_t ws_size,
                              hipStream_t stream) {
  const float* x      = (const float*)d_in[0];
  const int*   lens   = (const int*)d_in[1];
  const float* W_in   = (const float*)d_in[3];
  const float* b_in   = (const float*)d_in[4];
  const float* W_pass = (const float*)d_in[5];
  const float* b_pass = (const float*)d_in[6];
  const float* W_tau  = (const float*)d_in[7];
  const float* b_tau  = (const float*)d_in[8];
  const float* W_mem  = (const float*)d_in[9];
  const float* b_mem  = (const float*)d_in[10];
  const float* W_out  = (const float*)d_in[11];
  const float* b_out  = (const float*)d_in[12];

  char* ws = (char*)d_ws;
  size_t off = 0;
  int* arrive = (int*)(ws + off);                  off += 2048;   // 256 x 8B
  unsigned* h0a  = (unsigned*)(ws + off);          off += (size_t)kGrp * kWrd * 4;  // 64KB
  unsigned* h0b  = (unsigned*)(ws + off);          off += (size_t)kGrp * kWrd * 4;  // 64KB
  unsigned* h0am = (unsigned*)(ws + off);          off += (size_t)kGrp * kWrd * 4;  // 64KB
  unsigned* h0bm = (unsigned*)(ws + off);          off += (size_t)kGrp * kWrd * 4;  // 64KB
  float* bias = (float*)(ws + off);                off += 6 * kH * sizeof(float);
  __hip_bfloat16* WtOut = (__hip_bfloat16*)(ws + off); off += (size_t)kC * kH * 2;
  __hip_bfloat16* h0hist = (__hip_bfloat16*)(ws + off); off += (size_t)kOutL * kB * kH * 2;
  __hip_bfloat16* xb    = (__hip_bfloat16*)(ws + off); off += (size_t)kB * kS * kI * 2;
  __hip_bfloat16* Wall  = (__hip_bfloat16*)(ws + off); off += (size_t)6 * kH * kKz * 2;
  __hip_bfloat16* BtP   = (__hip_bfloat16*)(ws + off); off += (size_t)kH * kH * 2;
  __hip_bfloat16* BtT   = (__hip_bfloat16*)(ws + off); off += (size_t)kH * kH * 2;
  __hip_bfloat16* BtM   = (__hip_bfloat16*)(ws + off); off += (size_t)kH * kH * 2;
  __hip_bfloat16* Cip   = (__hip_bfloat16*)(ws + off); off += (size_t)kKz * kH * 2;

  // zero barrier flags + all four tagged h0 buffers (tag 0 == step-0 expectation)
  hipMemsetAsync(d_ws, 0, 2048 + 4 * (size_t)kGrp * kWrd * 4, stream);

  prep_cast<<<512, 256, 0, stream>>>(x, W_in, W_pass, W_tau, W_mem, W_out,
                                     xb, Wall, BtP, BtT, BtM, WtOut);
  prep_bias<<<1, 512, 0, stream>>>(b_in, b_pass, b_tau, b_mem, W_pass, W_tau, W_mem, bias);
  prep_mm1<<<dim3(40, 32, 3), 64, 0, stream>>>(W_in, BtP, BtT, BtM, Wall, Cip);
  prep_mm2<<<dim3(40, 32, 2), 64, 0, stream>>>(Cip, BtT, BtM, Wall);

  KParams P;
  P.xb = xb; P.Wall = Wall; P.WtOut = WtOut; P.bias = bias; P.b_out = b_out;
  P.h0a = h0a; P.h0b = h0b; P.h0am = h0am; P.h0bm = h0bm;
  P.h0hist = h0hist; P.arrive = arrive;
  P.lengths = lens; P.dout = (float*)d_out;

  rnn_main<<<dim3(kNWG), dim3(256), 0, stream>>>(P);
}

// Round 9
// 1091.730 us; speedup vs baseline: 5.2331x; 1.5915x over previous
//
#include <hip/hip_runtime.h>
#include <hip/hip_bf16.h>

// DelayRNN on MI355X — Round 23: lean device-scope exchange at the RTT floor.
// Protocol evidence (R18/R19/R21/R22): sc0/sc1 form a SCOPE field, not bypass
// bits. sc0-only=SE scope (no cross-CU freshness: R18 stale, R22 probes never
// hit); sc0+sc1=system scope via LLC (R19 works, 3.4us/step); atomics =
// memory-side (R21: 5.5GB writes, 4x slow); plain stores drain lazily (R22).
// No scope gives XCD-L2-coherent sync => the intra-XCD fast path does not
// exist on this part. Batch-partitioned alternatives need ~7.8us/step of
// single-CU MFMA (per-CU matrix pipe ~3378 FLOP/cyc) — worse than the RTT.
// R23 therefore strips all dead machinery (fast tier, mirrors, XCC check —
// ~390us of R22 overhead) and runs the proven exchange at sc1-only DEVICE
// scope (the memory-model-sufficient level; system scope may pay extra).
// Kept: weights in 120 VGPRs, 8 groups x 4 batches, 8KB tagged slab, fused
// detect+fetch polls, critical-path-first epilogue, snapshot + x-prefetch in
// the publish shadow, 319 steps, tail barrier + decode GEMM, spin caps.

constexpr int kB    = 32;
constexpr int kS    = 256;
constexpr int kI    = 128;
constexpr int kH    = 512;
constexpr int kC    = 64;
constexpr int kOutL = 64;
constexpr int kMaxD = 16;
constexpr int kBufD = 17;
constexpr int kNWG  = 256;
constexpr int kJPW  = 16;
constexpr int kGrp  = 8;                 // 8 groups x 4 batches (independent)
constexpr int kBpG  = kB / kGrp;
constexpr int kWrd  = kBpG * kH;         // 2048 tagged u32 per group slab (8KB)
constexpr int kSteps = kS + kOutL - 1;   // 319
constexpr int kKz   = kH + kI;           // 640
constexpr int kZPad = 8;
constexpr unsigned kSpinCap = 131072;    // poll cap — wedge-proof

typedef __bf16 bf16x8 __attribute__((ext_vector_type(8)));
typedef float  f32x4  __attribute__((ext_vector_type(4)));
typedef unsigned int u32x4 __attribute__((ext_vector_type(4)));

__device__ __forceinline__ f32x4 MFMA(bf16x8 a, bf16x8 b, f32x4 c) {
  return __builtin_amdgcn_mfma_f32_16x16x32_bf16(a, b, c, 0, 0, 0);
}
__device__ __forceinline__ bf16x8 ld8(const __hip_bfloat16* p) {
  return *reinterpret_cast<const bf16x8*>(p);
}
__device__ __forceinline__ bf16x8 ld8_f32(const float* p) {
  float4 a = *(const float4*)p, b = *(const float4*)(p + 4);
  union { __hip_bfloat16 h[8]; bf16x8 v; } c;
  c.h[0] = __float2bfloat16(a.x); c.h[1] = __float2bfloat16(a.y);
  c.h[2] = __float2bfloat16(a.z); c.h[3] = __float2bfloat16(a.w);
  c.h[4] = __float2bfloat16(b.x); c.h[5] = __float2bfloat16(b.y);
  c.h[6] = __float2bfloat16(b.z); c.h[7] = __float2bfloat16(b.w);
  return c.v;
}
__device__ __forceinline__ float sigm(float x) { return 1.0f / (1.0f + __expf(-x)); }

// ---------------- prep kernels (validated R2-R12, unchanged) ----------------

__global__ void prep_cast(const float* x, const float* W_in, const float* W_pass,
                          const float* W_tau, const float* W_mem, const float* W_out,
                          __hip_bfloat16* xb, __hip_bfloat16* Wall, __hip_bfloat16* BtP,
                          __hip_bfloat16* BtT, __hip_bfloat16* BtM, __hip_bfloat16* WtOut) {
  const int tid = blockIdx.x * blockDim.x + threadIdx.x;
  const int nth = gridDim.x * blockDim.x;
  for (int i = tid; i < kB * kS * kI; i += nth) xb[i] = __float2bfloat16(x[i]);
  for (int i = tid; i < kH * kKz; i += nth) {
    int j = i / kKz, k = i - j * kKz;
    Wall[i] = __float2bfloat16(W_in[k * kH + j]);
  }
  for (int i = tid; i < kH * kH; i += nth) {
    int j = i >> 9, k = i & 511;
    BtP[i] = __float2bfloat16(W_pass[k * kH + j]);
    BtT[i] = __float2bfloat16(W_tau[k * kH + j]);
    BtM[i] = __float2bfloat16(W_mem[k * kH + j]);
  }
  for (int i = tid; i < kC * kH; i += nth) {
    int c = i >> 9, k = i & 511;
    WtOut[i] = __float2bfloat16(W_out[k * kC + c]);
  }
}

__global__ void prep_bias(const float* b_in, const float* b_pass, const float* b_tau,
                          const float* b_mem, const float* W_pass, const float* W_tau,
                          const float* W_mem, float* bias) {
  __shared__ float bp_s[kH];
  const int j = threadIdx.x;
  float s1 = 0.f, s2 = 0.f, s3 = 0.f;
  for (int k = 0; k < kH; ++k) {
    float bi = b_in[k];
    s1 += bi * W_pass[k * kH + j];
    s2 += bi * W_tau[k * kH + j];
    s3 += bi * W_mem[k * kH + j];
  }
  float bP = s1 + b_pass[j];
  bias[j]          = b_in[j];
  bias[kH + j]     = bP;
  bias[2 * kH + j] = s2 + b_tau[j];
  bias[4 * kH + j] = s3 + b_mem[j];
  bp_s[j] = bP;
  __syncthreads();
  float s4 = 0.f, s5 = 0.f;
  for (int k = 0; k < kH; ++k) {
    float v = bp_s[k];
    s4 += v * W_tau[k * kH + j];
    s5 += v * W_mem[k * kH + j];
  }
  bias[3 * kH + j] = s4 + b_tau[j];
  bias[5 * kH + j] = s5 + b_mem[j];
}

__global__ __launch_bounds__(64) void prep_mm1(const float* W_in, const __hip_bfloat16* BtP,
    const __hip_bfloat16* BtT, const __hip_bfloat16* BtM,
    __hip_bfloat16* Wall, __hip_bfloat16* Cip) {
  const int bm = blockIdx.x, bn = blockIdx.y, z = blockIdx.z;
  const int lane = threadIdx.x;
  const int kq = (lane >> 4) * 8;
  const __hip_bfloat16* Bt = (z == 0) ? BtP : (z == 1 ? BtT : BtM);
  const int mat = (z == 0) ? 1 : (z == 1 ? 2 : 4);
  const float* arow = W_in + (size_t)(bm * 16 + (lane & 15)) * kH;
  const __hip_bfloat16* brow = Bt + (size_t)(bn * 16 + (lane & 15)) * kH;
  f32x4 acc = {0.f, 0.f, 0.f, 0.f};
  for (int i = 0; i < 16; ++i) {
    const int kk = i * 32 + kq;
    acc = MFMA(ld8_f32(arow + kk), ld8(brow + kk), acc);
  }
  const int rm = (lane >> 4) * 4, cn = lane & 15;
  union { __hip_bfloat16 h[4]; ushort4 s; } cv;
#pragma unroll
  for (int r = 0; r < 4; ++r) cv.h[r] = __float2bfloat16(acc[r]);
  __hip_bfloat16* wd = Wall + ((size_t)mat * kH + bn * 16 + cn) * kKz + bm * 16 + rm;
  *(ushort4*)wd = cv.s;
  if (z == 0) {
#pragma unroll
    for (int r = 0; r < 4; ++r)
      Cip[(size_t)(bm * 16 + rm + r) * kH + bn * 16 + cn] = cv.h[r];
  }
}

__global__ __launch_bounds__(64) void prep_mm2(const __hip_bfloat16* Cip,
    const __hip_bfloat16* BtT, const __hip_bfloat16* BtM, __hip_bfloat16* Wall) {
  const int bm = blockIdx.x, bn = blockIdx.y, z = blockIdx.z;
  const int lane = threadIdx.x;
  const int kq = (lane >> 4) * 8;
  const __hip_bfloat16* Bt = (z == 0) ? BtT : BtM;
  const int mat = (z == 0) ? 3 : 5;
  const __hip_bfloat16* arow = Cip + (size_t)(bm * 16 + (lane & 15)) * kH;
  const __hip_bfloat16* brow = Bt + (size_t)(bn * 16 + (lane & 15)) * kH;
  f32x4 acc = {0.f, 0.f, 0.f, 0.f};
  for (int i = 0; i < 16; ++i) {
    const int kk = i * 32 + kq;
    acc = MFMA(ld8(arow + kk), ld8(brow + kk), acc);
  }
  const int rm = (lane >> 4) * 4, cn = lane & 15;
  union { __hip_bfloat16 h[4]; ushort4 s; } cv;
#pragma unroll
  for (int r = 0; r < 4; ++r) cv.h[r] = __float2bfloat16(acc[r]);
  __hip_bfloat16* wd = Wall + ((size_t)mat * kH + bn * 16 + cn) * kKz + bm * 16 + rm;
  *(ushort4*)wd = cv.s;
}

// ---------------- main persistent kernel ----------------

struct KParams {
  const __hip_bfloat16* xb;       // bf16 input [B][S][I]
  const __hip_bfloat16* Wall;     // [6][512][640] composites, [col][k]
  const __hip_bfloat16* WtOut;    // [64][512]
  const float* bias;              // [6][512]
  const float* b_out;             // [64]
  unsigned* h0a;                  // ping: [8 grp][4][512] tagged words
  unsigned* h0b;                  // pong
  __hip_bfloat16* h0hist;         // [64][32][512] decode-entry snapshots
  int* arrive;                    // tail-barrier flags, 8B stride
  const int* lengths;
  float* dout;                    // [B][kOutL][C]
};

__global__ __launch_bounds__(256, 1) void rnn_main(KParams P) {
  __shared__ __align__(16) __hip_bfloat16 zs[16][kKz + kZPad];  // 20,736 B
  __shared__ __align__(16) float outLDS[6][4][16][4];           // [mat][wave][col][b]
  __shared__ int len_s[kBpG];

  const int tid = threadIdx.x;
  const int lane = tid & 63, wave = tid >> 6;
  const int kq = (lane >> 4) * 8;
  const int g    = blockIdx.x & 7;       // group id
  const int slot = blockIdx.x >> 3;      // [0,32): column slice within group
  const int jn   = slot * kJPW + (lane & 15);
  const int bg0  = kBpG * g;             // first global batch of group

  // ---- weight preload: wave w owns K in [w*160,(w+1)*160); 6 mats x 5 iters ----
  bf16x8 wreg[6][5];
#pragma unroll
  for (int m = 0; m < 6; ++m)
#pragma unroll
    for (int i = 0; i < 5; ++i)
      wreg[m][i] = ld8(P.Wall + ((size_t)m * kH + jn) * kKz + wave * 160 + i * 32 + kq);

  if (tid < kBpG) len_s[tid] = P.lengths[bg0 + tid];

  // zero zs rows 4..15 (unused MFMA A-rows must stay zero)
  for (int idx = tid; idx < 12 * (kKz + kZPad) / 2; idx += 256)
    ((unsigned*)&zs[4][0])[idx] = 0u;

  // stage x(0)
  if (tid < 64) {
    const int b = tid >> 4, seg = tid & 15;
    *(u32x4*)&zs[b][kH + seg * 8] =
        *(const u32x4*)(P.xb + ((size_t)(bg0 + b) * kS + 0) * kI + seg * 8);
  }

  float bufr[2][kBufD];
#pragma unroll
  for (int u = 0; u < 2; ++u)
#pragma unroll
    for (int d = 0; d < kBufD; ++d) bufr[u][d] = 0.f;

  const int eb = tid >> 3, epr = tid & 7;        // epilogue geometry (tid<32)
  const unsigned o0 = (unsigned)tid * 16u;
  const unsigned o1 = o0 + 4096u;
  unsigned* const h0a_g = P.h0a + (size_t)g * kWrd;
  unsigned* const h0b_g = P.h0b + (size_t)g * kWrd;

  bool dead = false;   // sticky: poll cap hit -> never block again (wedge-proof)

  for (int t = 0; t < kSteps; ++t) {
    const unsigned* h0r = (t & 1) ? h0b_g : h0a_g;
    unsigned*       h0w = (t & 1) ? h0a_g : h0b_g;
    const unsigned tga = ((unsigned)t) << 16;
    u32x4 c0, c1;

    // ---- fused detect+fetch: device-scope (sc1) poll of the 8KB slab.
    //      Every word self-validating: high 16 bits = step tag. ----
    for (unsigned spin = 0;; ++spin) {
      asm volatile(
          "global_load_dwordx4 %0, %2, %4 sc1\n\t"
          "global_load_dwordx4 %1, %3, %4 sc1\n\t"
          "s_waitcnt vmcnt(0)"
          : "=&v"(c0), "=&v"(c1)
          : "v"(o0), "v"(o1), "s"(h0r)
          : "memory");
      const unsigned bad = (c0.x ^ tga) | (c0.y ^ tga) | (c0.z ^ tga) | (c0.w ^ tga) |
                           (c1.x ^ tga) | (c1.y ^ tga) | (c1.z ^ tga) | (c1.w ^ tga);
      if ((bad & 0xffff0000u) == 0) break;
      if (dead || spin > kSpinCap) { dead = true; break; }
      __builtin_amdgcn_s_sleep(1);
    }
    { // unpack: word w of slab -> (b = w>>9, col = w&511)
      const int bb = tid >> 7, c4 = (tid & 127) * 4;
      *(uint2*)&zs[bb][c4] =
          make_uint2((c0.x & 0xffffu) | (c0.y << 16), (c0.z & 0xffffu) | (c0.w << 16));
      *(uint2*)&zs[2 + bb][c4] =
          make_uint2((c1.x & 0xffffu) | (c1.y << 16), (c1.z & 0xffffu) | (c1.w << 16));
    }
    __syncthreads();

    // ---- GEMM: K split 4-ways across waves, weights in registers ----
    f32x4 a0 = {0.f,0.f,0.f,0.f}, a1 = {0.f,0.f,0.f,0.f}, a2 = {0.f,0.f,0.f,0.f};
    f32x4 a3 = {0.f,0.f,0.f,0.f}, a4 = {0.f,0.f,0.f,0.f}, a5 = {0.f,0.f,0.f,0.f};
    {
      const int ar = lane & 15;
      const int kb = wave * 160 + kq;
#pragma unroll
      for (int i = 0; i < 5; ++i) {
        const bf16x8 av = *(const bf16x8*)&zs[ar][kb + i * 32];
        a0 = MFMA(av, wreg[0][i], a0);
        a1 = MFMA(av, wreg[1][i], a1);
        a2 = MFMA(av, wreg[2][i], a2);
        a3 = MFMA(av, wreg[3][i], a3);
        a4 = MFMA(av, wreg[4][i], a4);
        a5 = MFMA(av, wreg[5][i], a5);
      }
    }
    // rows 0-3 (the 4 real batches) land in quarter-0 lanes: acc[r]=row r, col=lane
    if (lane < 16) {
      *(f32x4*)&outLDS[0][wave][lane][0] = a0;
      *(f32x4*)&outLDS[1][wave][lane][0] = a1;
      *(f32x4*)&outLDS[2][wave][lane][0] = a2;
      *(f32x4*)&outLDS[3][wave][lane][0] = a3;
      *(f32x4*)&outLDS[4][wave][lane][0] = a4;
      *(f32x4*)&outLDS[5][wave][lane][0] = a5;
    }
    __syncthreads();

    // ---- epilogue 1 (critical path): gates -> front -> tagged publish ----
    if (tid < 32) {
      const bool msk = (t >= kS) || (t < len_s[eb]);
      float hv2[2], tau2[2], ml2[2];
      unsigned short bits[2];
#pragma unroll
      for (int u = 0; u < 2; ++u) {
        const int cl = epr * 2 + u, j = slot * kJPW + cl;
        float s0 = outLDS[0][0][cl][eb] + outLDS[0][1][cl][eb] + outLDS[0][2][cl][eb] + outLDS[0][3][cl][eb];
        float s1 = outLDS[1][0][cl][eb] + outLDS[1][1][cl][eb] + outLDS[1][2][cl][eb] + outLDS[1][3][cl][eb];
        float s2 = outLDS[2][0][cl][eb] + outLDS[2][1][cl][eb] + outLDS[2][2][cl][eb] + outLDS[2][3][cl][eb];
        float s3 = outLDS[3][0][cl][eb] + outLDS[3][1][cl][eb] + outLDS[3][2][cl][eb] + outLDS[3][3][cl][eb];
        float s4 = outLDS[4][0][cl][eb] + outLDS[4][1][cl][eb] + outLDS[4][2][cl][eb] + outLDS[4][3][cl][eb];
        float s5 = outLDS[5][0][cl][eb] + outLDS[5][1][cl][eb] + outLDS[5][2][cl][eb] + outLDS[5][3][cl][eb];
        const float hp = s0 + P.bias[j];
        const float pv = s1 + P.bias[kH + j];
        const float ta = s2 + P.bias[2 * kH + j];
        const float tb = s3 + P.bias[3 * kH + j];
        const float ma = s4 + P.bias[4 * kH + j];
        const float mb = s5 + P.bias[5 * kH + j];
        const float hv = msk ? pv : hp;
        const float gt = msk ? tb : ta;
        const float gm = msk ? mb : ma;
        float tau = 16.f * sigm(gt);
        tau = fminf(fmaxf(tau, 1.f), 16.f);
        const float ml = sigm(gm);
        hv2[u] = hv; tau2[u] = tau; ml2[u] = ml;
        const float front = bufr[u][1] + (ml / (1.f + fabsf(tau - 1.f))) * hv;
        const __hip_bfloat16 hb = __float2bfloat16(front);
        unsigned short bt;
        __builtin_memcpy(&bt, &hb, 2);
        bits[u] = bt;
      }
      // publish: tag (t+1) in high 16 bits of each word; device scope (sc1)
      const unsigned tagp = ((unsigned)(t + 1)) << 16;
      const unsigned long long pk =
          ((unsigned long long)(tagp | bits[1]) << 32) | (tagp | bits[0]);
      const unsigned po = (unsigned)((eb * kH + slot * kJPW + epr * 2) * 4);
      asm volatile("global_store_dwordx2 %0, %1, %2 sc1"
                   :: "v"(po), "v"(pk), "s"(h0w) : "memory");

      // ---- epilogue 2 (in the shadow): shift + snapshot ----
#pragma unroll
      for (int u = 0; u < 2; ++u) {
#pragma unroll
        for (int d = 1; d <= kMaxD; ++d) {
          const float w = ml2[u] / (1.f + fabsf(tau2[u] - (float)d));
          bufr[u][d - 1] = bufr[u][d] + w * hv2[u];
        }
        bufr[u][kMaxD] = 0.f;
      }
      if ((unsigned)(t - (kS - 1)) < (unsigned)kOutL) {
        const unsigned hv = ((unsigned)bits[1] << 16) | bits[0];
        unsigned* hp2 =
            (unsigned*)(P.h0hist + ((size_t)(t - (kS - 1)) * kB + (bg0 + eb)) * kH) +
            (slot * 8 + epr);
        __hip_atomic_store(hp2, hv, __ATOMIC_RELAXED, __HIP_MEMORY_SCOPE_AGENT);
      }
    } else if (wave == 1) {
      // x prefetch for t+1 (x-cols disjoint from unpack cols; ordered by next barrier)
      const int tn = t + 1;
      const int b = (tid >> 4) & 3, seg = tid & 15;
      if (tn < kS) {
        *(u32x4*)&zs[b][kH + seg * 8] =
            *(const u32x4*)(P.xb + ((size_t)(bg0 + b) * kS + tn) * kI + seg * 8);
      } else if (tn == kS) {
        const u32x4 zv = {0u, 0u, 0u, 0u};
        *(u32x4*)&zs[b][kH + seg * 8] = zv;
      }
    }
    // no trailing barrier: dataflow tags order everything within the group.
  }

  // ---- tail: one grid barrier, then decode-output GEMM on WGs 0..31 ----
  __builtin_amdgcn_s_waitcnt(0);
  __syncthreads();
  const int wg = blockIdx.x;
  if (tid == 0)
    __hip_atomic_store(&P.arrive[wg * 2], 1, __ATOMIC_RELAXED, __HIP_MEMORY_SCOPE_AGENT);
  if (tid < kNWG) {
    unsigned spin = 0;
    while (__hip_atomic_load(&P.arrive[tid * 2],
                             __ATOMIC_RELAXED, __HIP_MEMORY_SCOPE_AGENT) < 1) {
      if (++spin > kSpinCap * 16u) break;   // bounded even here
      __builtin_amdgcn_s_sleep(2);
    }
  }
  __syncthreads();
  if (wg >= 32) return;

  // dout[b][td][c] = h0hist[td][b][:] @ WtOut[c][:] + b_out[c]
  {
    const int q = lane >> 4, r = lane & 15;
    const int mrow = wg * 64 + wave * 16 + r;   // m = td*32 + b
    const char* ap = (const char*)P.h0hist + (size_t)mrow * 1024 + q * 16;
    u32x4 d0, d1, d2, d3, d4, d5, d6, d7, d8, d9, dA, dB, dC, dD, dE, dF;
    asm volatile(
        "global_load_dwordx4 %0, %16, off sc0 sc1\n\t"
        "global_load_dwordx4 %1, %16, off offset:64 sc0 sc1\n\t"
        "global_load_dwordx4 %2, %16, off offset:128 sc0 sc1\n\t"
        "global_load_dwordx4 %3, %16, off offset:192 sc0 sc1\n\t"
        "global_load_dwordx4 %4, %16, off offset:256 sc0 sc1\n\t"
        "global_load_dwordx4 %5, %16, off offset:320 sc0 sc1\n\t"
        "global_load_dwordx4 %6, %16, off offset:384 sc0 sc1\n\t"
        "global_load_dwordx4 %7, %16, off offset:448 sc0 sc1\n\t"
        "global_load_dwordx4 %8, %16, off offset:512 sc0 sc1\n\t"
        "global_load_dwordx4 %9, %16, off offset:576 sc0 sc1\n\t"
        "global_load_dwordx4 %10, %16, off offset:640 sc0 sc1\n\t"
        "global_load_dwordx4 %11, %16, off offset:704 sc0 sc1\n\t"
        "global_load_dwordx4 %12, %16, off offset:768 sc0 sc1\n\t"
        "global_load_dwordx4 %13, %16, off offset:832 sc0 sc1\n\t"
        "global_load_dwordx4 %14, %16, off offset:896 sc0 sc1\n\t"
        "global_load_dwordx4 %15, %16, off offset:960 sc0 sc1\n\t"
        "s_waitcnt vmcnt(0)"
        : "=&v"(d0), "=&v"(d1), "=&v"(d2), "=&v"(d3),
          "=&v"(d4), "=&v"(d5), "=&v"(d6), "=&v"(d7),
          "=&v"(d8), "=&v"(d9), "=&v"(dA), "=&v"(dB),
          "=&v"(dC), "=&v"(dD), "=&v"(dE), "=&v"(dF)
        : "v"(ap)
        : "memory");
    union { u32x4 u; bf16x8 v; } av[16] = {{d0},{d1},{d2},{d3},{d4},{d5},{d6},{d7},
                                           {d8},{d9},{dA},{dB},{dC},{dD},{dE},{dF}};
    f32x4 T0 = {0.f,0.f,0.f,0.f}, T1 = {0.f,0.f,0.f,0.f};
    f32x4 T2 = {0.f,0.f,0.f,0.f}, T3 = {0.f,0.f,0.f,0.f};
#pragma unroll
    for (int ik = 0; ik < 16; ++ik) {
      const int kk = ik * 32 + kq;
      const __hip_bfloat16* wb = P.WtOut + (size_t)r * kH + kk;
      T0 = MFMA(av[ik].v, ld8(wb), T0);
      T1 = MFMA(av[ik].v, ld8(wb + 16 * kH), T1);
      T2 = MFMA(av[ik].v, ld8(wb + 32 * kH), T2);
      T3 = MFMA(av[ik].v, ld8(wb + 48 * kH), T3);
    }
    f32x4 T[4] = {T0, T1, T2, T3};
#pragma unroll
    for (int ct = 0; ct < 4; ++ct) {
      const int c = ct * 16 + r;
      const float bo = P.b_out[c];
#pragma unroll
      for (int rr = 0; rr < 4; ++rr) {
        const int m = wg * 64 + wave * 16 + q * 4 + rr;
        const int b = m & 31, td = m >> 5;
        P.dout[(size_t)b * (kOutL * kC) + td * kC + c] = T[ct][rr] + bo;
      }
    }
  }
}

extern "C" void kernel_launch(void* const* d_in, const int* in_sizes, int n_in,
                              void* d_out, int out_size, void* d_ws, size_t ws_size,
                              hipStream_t stream) {
  const float* x      = (const float*)d_in[0];
  const int*   lens   = (const int*)d_in[1];
  const float* W_in   = (const float*)d_in[3];
  const float* b_in   = (const float*)d_in[4];
  const float* W_pass = (const float*)d_in[5];
  const float* b_pass = (const float*)d_in[6];
  const float* W_tau  = (const float*)d_in[7];
  const float* b_tau  = (const float*)d_in[8];
  const float* W_mem  = (const float*)d_in[9];
  const float* b_mem  = (const float*)d_in[10];
  const float* W_out  = (const float*)d_in[11];
  const float* b_out  = (const float*)d_in[12];

  char* ws = (char*)d_ws;
  size_t off = 0;
  int* arrive = (int*)(ws + off);                  off += 2048;   // 256 x 8B
  unsigned* h0a = (unsigned*)(ws + off);           off += (size_t)kGrp * kWrd * 4;  // 64KB
  unsigned* h0b = (unsigned*)(ws + off);           off += (size_t)kGrp * kWrd * 4;  // 64KB
  float* bias = (float*)(ws + off);                off += 6 * kH * sizeof(float);
  __hip_bfloat16* WtOut = (__hip_bfloat16*)(ws + off); off += (size_t)kC * kH * 2;
  __hip_bfloat16* h0hist = (__hip_bfloat16*)(ws + off); off += (size_t)kOutL * kB * kH * 2;
  __hip_bfloat16* xb    = (__hip_bfloat16*)(ws + off); off += (size_t)kB * kS * kI * 2;
  __hip_bfloat16* Wall  = (__hip_bfloat16*)(ws + off); off += (size_t)6 * kH * kKz * 2;
  __hip_bfloat16* BtP   = (__hip_bfloat16*)(ws + off); off += (size_t)kH * kH * 2;
  __hip_bfloat16* BtT   = (__hip_bfloat16*)(ws + off); off += (size_t)kH * kH * 2;
  __hip_bfloat16* BtM   = (__hip_bfloat16*)(ws + off); off += (size_t)kH * kH * 2;
  __hip_bfloat16* Cip   = (__hip_bfloat16*)(ws + off); off += (size_t)kKz * kH * 2;

  // zero barrier flags + both tagged h0 buffers (tag 0 == step-0 expectation)
  hipMemsetAsync(d_ws, 0, 2048 + 2 * (size_t)kGrp * kWrd * 4, stream);

  prep_cast<<<512, 256, 0, stream>>>(x, W_in, W_pass, W_tau, W_mem, W_out,
                                     xb, Wall, BtP, BtT, BtM, WtOut);
  prep_bias<<<1, 512, 0, stream>>>(b_in, b_pass, b_tau, b_mem, W_pass, W_tau, W_mem, bias);
  prep_mm1<<<dim3(40, 32, 3), 64, 0, stream>>>(W_in, BtP, BtT, BtM, Wall, Cip);
  prep_mm2<<<dim3(40, 32, 2), 64, 0, stream>>>(Cip, BtT, BtM, Wall);

  KParams P;
  P.xb = xb; P.Wall = Wall; P.WtOut = WtOut; P.bias = bias; P.b_out = b_out;
  P.h0a = h0a; P.h0b = h0b; P.h0hist = h0hist; P.arrive = arrive;
  P.lengths = lens; P.dout = (float*)d_out;

  rnn_main<<<dim3(kNWG), dim3(256), 0, stream>>>(P);
}